// Round 1
// baseline (3462.391 us; speedup 1.0000x reference)
//
#include <hip/hip_runtime.h>

#define NN   100000
#define EMB  64
#define HID  128
#define OUTD 64
#define NE   1600000
#define NL   200000

// ---------------- degree ----------------
__global__ void deg_kernel(const int* __restrict__ dst, float* __restrict__ deg) {
    int i = blockIdx.x * blockDim.x + threadIdx.x;
    int stride = gridDim.x * blockDim.x;
    for (; i < NE; i += stride)
        atomicAdd(&deg[dst[i]], 1.0f);
}

__global__ void inv_kernel(float* __restrict__ deg) {
    int i = blockIdx.x * blockDim.x + threadIdx.x;
    if (i < NN) deg[i] = 1.0f / fmaxf(deg[i], 1.0f);
}

// ---------------- scatter-add of 64-dim rows: agg[dst] += x[src] ----------------
__global__ void scatter64_kernel(const int* __restrict__ src, const int* __restrict__ dst,
                                 const float* __restrict__ x, float* __restrict__ agg) {
    int i = blockIdx.x * blockDim.x + threadIdx.x;
    int stride = gridDim.x * blockDim.x;
    const int total = NE * 16;  // 16 float4 slots per edge
    for (; i < total; i += stride) {
        int e = i >> 4;
        int q = i & 15;
        int s = src[e], d = dst[e];
        float4 v = ((const float4*)x)[s * 16 + q];
        float* a = &agg[(size_t)d * 64 + q * 4];
        atomicAdd(a + 0, v.x);
        atomicAdd(a + 1, v.y);
        atomicAdd(a + 2, v.z);
        atomicAdd(a + 3, v.w);
    }
}

// ---------------- layer 1: h = relu(agg1*inv_deg @ w1l^T + emb @ w1r^T + b1) ----------------
// 128 threads/block, thread o owns weight rows w1l[o][:], w1r[o][:] in VGPRs.
__global__ void __launch_bounds__(128) layer1_kernel(
        const float* __restrict__ agg1, const float* __restrict__ emb,
        const float* __restrict__ inv_deg,
        const float* __restrict__ w1l, const float* __restrict__ w1r,
        const float* __restrict__ b1, float* __restrict__ h, int npb) {
    const int o = threadIdx.x;  // 0..127
    float wl[EMB], wr[EMB];
#pragma unroll
    for (int c = 0; c < EMB; ++c) {
        wl[c] = w1l[o * EMB + c];
        wr[c] = w1r[o * EMB + c];
    }
    const float bias = b1[o];
    int start = blockIdx.x * npb;
    int end = min(start + npb, NN);
    for (int node = start; node < end; ++node) {
        const float s = inv_deg[node];                 // wave-uniform
        const float* xa = agg1 + (size_t)node * EMB;   // wave-uniform base -> s_load
        const float* xe = emb + (size_t)node * EMB;
        float acc1 = 0.f, acc2 = 0.f;
#pragma unroll
        for (int c = 0; c < EMB; ++c) {
            acc1 += xa[c] * wl[c];
            acc2 += xe[c] * wr[c];
        }
        float v = bias + acc1 * s + acc2;
        h[(size_t)node * HID + o] = fmaxf(v, 0.f);
    }
}

// ---------------- p2 = h @ w2l^T  (no bias; aggregated afterwards) ----------------
// 256 threads: o = tid&63, 4 nodes in flight (tid>>6).
__global__ void __launch_bounds__(256) p2_kernel(
        const float* __restrict__ h, const float* __restrict__ w2l,
        float* __restrict__ p2, int npb) {
    const int o = threadIdx.x & 63;
    const int sub = threadIdx.x >> 6;  // 0..3
    float w[HID];
#pragma unroll
    for (int c = 0; c < HID; ++c) w[c] = w2l[o * HID + c];
    int start = blockIdx.x * npb;
    int end = min(start + npb, NN);
    for (int node = start + sub; node < end; node += 4) {
        const float* x = h + (size_t)node * HID;  // wave-uniform
        float acc = 0.f;
#pragma unroll
        for (int c = 0; c < HID; ++c) acc += x[c] * w[c];
        p2[(size_t)node * OUTD + o] = acc;
    }
}

// ---------------- z = agg2*inv_deg + h @ w2r^T + b2 ----------------
__global__ void __launch_bounds__(256) z_kernel(
        const float* __restrict__ agg2, const float* __restrict__ h,
        const float* __restrict__ inv_deg, const float* __restrict__ w2r,
        const float* __restrict__ b2, float* __restrict__ z, int npb) {
    const int o = threadIdx.x & 63;
    const int sub = threadIdx.x >> 6;
    float w[HID];
#pragma unroll
    for (int c = 0; c < HID; ++c) w[c] = w2r[o * HID + c];
    const float bias = b2[o];
    int start = blockIdx.x * npb;
    int end = min(start + npb, NN);
    for (int node = start + sub; node < end; node += 4) {
        const float* x = h + (size_t)node * HID;
        float acc = 0.f;
#pragma unroll
        for (int c = 0; c < HID; ++c) acc += x[c] * w[c];
        z[(size_t)node * OUTD + o] =
            acc + bias + agg2[(size_t)node * OUTD + o] * inv_deg[node];
    }
}

// ---------------- decode: out[k] = dot(z[a[k]], z[b[k]]) ----------------
// 16 lanes per pair, float4 each, shfl_xor reduce.
__global__ void decode_kernel(const int* __restrict__ a, const int* __restrict__ b,
                              const float* __restrict__ z, float* __restrict__ out) {
    int t = blockIdx.x * blockDim.x + threadIdx.x;
    int k = t >> 4;
    int q = t & 15;
    if (k >= NL) return;
    int ia = a[k], ib = b[k];
    float4 va = ((const float4*)z)[ia * 16 + q];
    float4 vb = ((const float4*)z)[ib * 16 + q];
    float s = va.x * vb.x + va.y * vb.y + va.z * vb.z + va.w * vb.w;
    s += __shfl_xor(s, 1, 64);
    s += __shfl_xor(s, 2, 64);
    s += __shfl_xor(s, 4, 64);
    s += __shfl_xor(s, 8, 64);
    if (q == 0) out[k] = s;
}

extern "C" void kernel_launch(void* const* d_in, const int* in_sizes, int n_in,
                              void* d_out, int out_size, void* d_ws, size_t ws_size,
                              hipStream_t stream) {
    const float* emb = (const float*)d_in[0];
    const float* w1l = (const float*)d_in[1];
    const float* w1r = (const float*)d_in[2];
    const float* b1  = (const float*)d_in[3];
    const float* w2l = (const float*)d_in[4];
    const float* w2r = (const float*)d_in[5];
    const float* b2  = (const float*)d_in[6];
    const int*   ei  = (const int*)d_in[7];
    const int*   eli = (const int*)d_in[8];
    float* out = (float*)d_out;

    float* ws   = (float*)d_ws;
    float* deg  = ws;                          // NN
    float* agg1 = ws + NN;                     // NN*64 (reused as z)
    float* h    = agg1 + (size_t)NN * 64;      // NN*128
    float* p2   = h + (size_t)NN * 128;        // NN*64
    float* agg2 = p2 + (size_t)NN * 64;        // NN*64
    float* z    = agg1;                        // reuse after layer1 consumed agg1

    hipMemsetAsync(deg, 0, NN * sizeof(float), stream);
    hipMemsetAsync(agg1, 0, (size_t)NN * 64 * sizeof(float), stream);
    hipMemsetAsync(agg2, 0, (size_t)NN * 64 * sizeof(float), stream);

    const int* src = ei;
    const int* dst = ei + NE;

    deg_kernel<<<2048, 256, 0, stream>>>(dst, deg);
    inv_kernel<<<(NN + 255) / 256, 256, 0, stream>>>(deg);

    scatter64_kernel<<<4096, 256, 0, stream>>>(src, dst, emb, agg1);

    int npb1 = (NN + 2047) / 2048;
    layer1_kernel<<<2048, 128, 0, stream>>>(agg1, emb, deg, w1l, w1r, b1, h, npb1);

    int npb2 = (NN + 1023) / 1024;
    p2_kernel<<<1024, 256, 0, stream>>>(h, w2l, p2, npb2);

    scatter64_kernel<<<4096, 256, 0, stream>>>(src, dst, p2, agg2);

    z_kernel<<<1024, 256, 0, stream>>>(agg2, h, deg, w2r, b2, z, npb2);

    decode_kernel<<<(NL * 16 + 255) / 256, 256, 0, stream>>>(eli, eli + NL, z, out);
}

// Round 2
// 1274.866 us; speedup vs baseline: 2.7159x; 2.7159x over previous
//
#include <hip/hip_runtime.h>

#define NN   100000
#define EMB  64
#define HID  128
#define OUTD 64
#define NE   1600000
#define NL   200000
#define NCH  196   // ceil(NN/512) scan chunks

// ---------------- degree histogram (int) ----------------
__global__ void deg_kernel(const int* __restrict__ dst, int* __restrict__ deg) {
    int i = blockIdx.x * blockDim.x + threadIdx.x;
    int stride = gridDim.x * blockDim.x;
    for (; i < NE; i += stride)
        atomicAdd(&deg[dst[i]], 1);
}

__global__ void inv_kernel(const int* __restrict__ deg, float* __restrict__ inv_deg) {
    int i = blockIdx.x * blockDim.x + threadIdx.x;
    if (i < NN) inv_deg[i] = 1.0f / fmaxf((float)deg[i], 1.0f);
}

// ---------------- 2-level exclusive scan: deg -> rowptr ----------------
__global__ void partial_kernel(const int* __restrict__ deg, int* __restrict__ partial) {
    int base = blockIdx.x * 512;
    int s = 0;
    for (int k = threadIdx.x; k < 512; k += 256) {
        int idx = base + k;
        if (idx < NN) s += deg[idx];
    }
    __shared__ int red[256];
    red[threadIdx.x] = s;
    __syncthreads();
    for (int off = 128; off > 0; off >>= 1) {
        if (threadIdx.x < off) red[threadIdx.x] += red[threadIdx.x + off];
        __syncthreads();
    }
    if (threadIdx.x == 0) partial[blockIdx.x] = red[0];
}

__global__ void scanp_kernel(int* __restrict__ partial, int* __restrict__ rowptr) {
    if (threadIdx.x == 0 && blockIdx.x == 0) {
        int acc = 0;
        for (int i = 0; i < NCH; ++i) {
            int v = partial[i];
            partial[i] = acc;
            acc += v;
        }
        rowptr[NN] = NE;
    }
}

__global__ void scanf_kernel(const int* __restrict__ deg, const int* __restrict__ partial,
                             int* __restrict__ rowptr) {
    __shared__ int buf[512];
    int t = threadIdx.x;
    int idx = blockIdx.x * 512 + t;
    int v = (idx < NN) ? deg[idx] : 0;
    buf[t] = v;
    __syncthreads();
    for (int off = 1; off < 512; off <<= 1) {
        int add = (t >= off) ? buf[t - off] : 0;
        __syncthreads();
        buf[t] += add;
        __syncthreads();
    }
    if (idx < NN) rowptr[idx] = buf[t] - v + partial[blockIdx.x];
}

// ---------------- CSR fill ----------------
__global__ void fill_kernel(const int* __restrict__ src, const int* __restrict__ dst,
                            const int* __restrict__ rowptr, int* __restrict__ cursor,
                            int* __restrict__ col) {
    int i = blockIdx.x * blockDim.x + threadIdx.x;
    int stride = gridDim.x * blockDim.x;
    for (; i < NE; i += stride) {
        int d = dst[i];
        int pos = atomicAdd(&cursor[d], 1);
        col[rowptr[d] + pos] = src[i];
    }
}

// ---------------- gather-sum: out[i] = inv_deg[i] * sum_{j in N(i)} x[j]  (64-dim rows) ----------------
__global__ void gather_kernel(const int* __restrict__ rowptr, const int* __restrict__ col,
                              const float* __restrict__ x, const float* __restrict__ inv_deg,
                              float* __restrict__ out) {
    int wave = (blockIdx.x * blockDim.x + threadIdx.x) >> 6;
    int lane = threadIdx.x & 63;
    if (wave >= NN) return;
    int s = rowptr[wave], e = rowptr[wave + 1];
    float acc = 0.f;
    for (int j = s; j < e; ++j) {
        int c = col[j];  // wave-uniform -> broadcast
        acc += x[(size_t)c * 64 + lane];
    }
    out[(size_t)wave * 64 + lane] = acc * inv_deg[wave];
}

// ---------------- layer 1: h = relu(agg1 @ w1l^T + emb @ w1r^T + b1) ----------------
__global__ void __launch_bounds__(128) layer1_kernel(
        const float* __restrict__ agg1, const float* __restrict__ emb,
        const float* __restrict__ w1l, const float* __restrict__ w1r,
        const float* __restrict__ b1, float* __restrict__ h, int npb) {
    const int o = threadIdx.x;  // 0..127
    float wl[EMB], wr[EMB];
#pragma unroll
    for (int c = 0; c < EMB; ++c) {
        wl[c] = w1l[o * EMB + c];
        wr[c] = w1r[o * EMB + c];
    }
    const float bias = b1[o];
    int start = blockIdx.x * npb;
    int end = min(start + npb, NN);
    for (int node = start; node < end; ++node) {
        const float* xa = agg1 + (size_t)node * EMB;  // wave-uniform
        const float* xe = emb + (size_t)node * EMB;
        float acc1 = 0.f, acc2 = 0.f;
#pragma unroll
        for (int c = 0; c < EMB; ++c) {
            acc1 += xa[c] * wl[c];
            acc2 += xe[c] * wr[c];
        }
        float v = bias + acc1 + acc2;
        h[(size_t)node * HID + o] = fmaxf(v, 0.f);
    }
}

// ---------------- p2 = h @ w2l^T ----------------
__global__ void __launch_bounds__(256) p2_kernel(
        const float* __restrict__ h, const float* __restrict__ w2l,
        float* __restrict__ p2, int npb) {
    const int o = threadIdx.x & 63;
    const int sub = threadIdx.x >> 6;
    float w[HID];
#pragma unroll
    for (int c = 0; c < HID; ++c) w[c] = w2l[o * HID + c];
    int start = blockIdx.x * npb;
    int end = min(start + npb, NN);
    for (int node = start + sub; node < end; node += 4) {
        const float* x = h + (size_t)node * HID;
        float acc = 0.f;
#pragma unroll
        for (int c = 0; c < HID; ++c) acc += x[c] * w[c];
        p2[(size_t)node * OUTD + o] = acc;
    }
}

// ---------------- z = agg2 + h @ w2r^T + b2  (in-place on agg2 allowed) ----------------
__global__ void __launch_bounds__(256) z_kernel(
        const float* __restrict__ agg2, const float* __restrict__ h,
        const float* __restrict__ w2r, const float* __restrict__ b2,
        float* __restrict__ z, int npb) {
    const int o = threadIdx.x & 63;
    const int sub = threadIdx.x >> 6;
    float w[HID];
#pragma unroll
    for (int c = 0; c < HID; ++c) w[c] = w2r[o * HID + c];
    const float bias = b2[o];
    int start = blockIdx.x * npb;
    int end = min(start + npb, NN);
    for (int node = start + sub; node < end; node += 4) {
        const float* x = h + (size_t)node * HID;
        float acc = 0.f;
#pragma unroll
        for (int c = 0; c < HID; ++c) acc += x[c] * w[c];
        z[(size_t)node * OUTD + o] = acc + bias + agg2[(size_t)node * OUTD + o];
    }
}

// ---------------- decode: out[k] = dot(z[a[k]], z[b[k]]) ----------------
__global__ void decode_kernel(const int* __restrict__ a, const int* __restrict__ b,
                              const float* __restrict__ z, float* __restrict__ out) {
    int t = blockIdx.x * blockDim.x + threadIdx.x;
    int k = t >> 4;
    int q = t & 15;
    if (k >= NL) return;
    int ia = a[k], ib = b[k];
    float4 va = ((const float4*)z)[ia * 16 + q];
    float4 vb = ((const float4*)z)[ib * 16 + q];
    float s = va.x * vb.x + va.y * vb.y + va.z * vb.z + va.w * vb.w;
    s += __shfl_xor(s, 1, 64);
    s += __shfl_xor(s, 2, 64);
    s += __shfl_xor(s, 4, 64);
    s += __shfl_xor(s, 8, 64);
    if (q == 0) out[k] = s;
}

extern "C" void kernel_launch(void* const* d_in, const int* in_sizes, int n_in,
                              void* d_out, int out_size, void* d_ws, size_t ws_size,
                              hipStream_t stream) {
    const float* emb = (const float*)d_in[0];
    const float* w1l = (const float*)d_in[1];
    const float* w1r = (const float*)d_in[2];
    const float* b1  = (const float*)d_in[3];
    const float* w2l = (const float*)d_in[4];
    const float* w2r = (const float*)d_in[5];
    const float* b2  = (const float*)d_in[6];
    const int*   ei  = (const int*)d_in[7];
    const int*   eli = (const int*)d_in[8];
    float* out = (float*)d_out;

    // workspace layout (~110.4 MB)
    int* ideg    = (int*)d_ws;                 // NN
    int* rowptr  = ideg + NN;                  // NN+1
    int* cursor  = rowptr + NN + 1;            // NN
    int* partial = cursor + NN;                // 256
    int* col     = partial + 256;              // NE
    float* inv_deg = (float*)(col + NE);       // NN
    float* agg   = inv_deg + NN;               // NN*64  (agg1, then agg2, then z in-place)
    float* h     = agg + (size_t)NN * 64;      // NN*128
    float* p2    = h + (size_t)NN * 128;       // NN*64
    float* z     = agg;

    const int* src = ei;
    const int* dst = ei + NE;

    hipMemsetAsync(ideg, 0, NN * sizeof(int), stream);
    hipMemsetAsync(cursor, 0, NN * sizeof(int), stream);

    // CSR build
    deg_kernel<<<2048, 256, 0, stream>>>(dst, ideg);
    inv_kernel<<<(NN + 255) / 256, 256, 0, stream>>>(ideg, inv_deg);
    partial_kernel<<<NCH, 256, 0, stream>>>(ideg, partial);
    scanp_kernel<<<1, 64, 0, stream>>>(partial, rowptr);
    scanf_kernel<<<NCH, 512, 0, stream>>>(ideg, partial, rowptr);
    fill_kernel<<<2048, 256, 0, stream>>>(src, dst, rowptr, cursor, col);

    // layer 1
    gather_kernel<<<(NN * 64 + 255) / 256, 256, 0, stream>>>(rowptr, col, emb, inv_deg, agg);
    int npb1 = (NN + 2047) / 2048;
    layer1_kernel<<<2048, 128, 0, stream>>>(agg, emb, w1l, w1r, b1, h, npb1);

    // layer 2
    int npb2 = (NN + 1023) / 1024;
    p2_kernel<<<1024, 256, 0, stream>>>(h, w2l, p2, npb2);
    gather_kernel<<<(NN * 64 + 255) / 256, 256, 0, stream>>>(rowptr, col, p2, inv_deg, agg);
    z_kernel<<<1024, 256, 0, stream>>>(agg, h, w2r, b2, z, npb2);

    // decode
    decode_kernel<<<(NL * 16 + 255) / 256, 256, 0, stream>>>(eli, eli + NL, z, out);
}

// Round 3
// 639.677 us; speedup vs baseline: 5.4127x; 1.9930x over previous
//
#include <hip/hip_runtime.h>

#define NN   100000
#define EMB  64
#define HID  128
#define OUTD 64
#define NE   1600000
#define NL   200000
#define NCH  196   // ceil(NN/512) scan chunks

// ---------------- degree histogram (int) ----------------
__global__ void deg_kernel(const int* __restrict__ dst, int* __restrict__ deg) {
    int i = blockIdx.x * blockDim.x + threadIdx.x;
    int stride = gridDim.x * blockDim.x;
    for (; i < NE; i += stride)
        atomicAdd(&deg[dst[i]], 1);
}

__global__ void inv_kernel(const int* __restrict__ deg, float* __restrict__ inv_deg) {
    int i = blockIdx.x * blockDim.x + threadIdx.x;
    if (i < NN) inv_deg[i] = 1.0f / fmaxf((float)deg[i], 1.0f);
}

// ---------------- 2-level exclusive scan: deg -> rowptr ----------------
__global__ void partial_kernel(const int* __restrict__ deg, int* __restrict__ partial) {
    int base = blockIdx.x * 512;
    int s = 0;
    for (int k = threadIdx.x; k < 512; k += 256) {
        int idx = base + k;
        if (idx < NN) s += deg[idx];
    }
    __shared__ int red[256];
    red[threadIdx.x] = s;
    __syncthreads();
    for (int off = 128; off > 0; off >>= 1) {
        if (threadIdx.x < off) red[threadIdx.x] += red[threadIdx.x + off];
        __syncthreads();
    }
    if (threadIdx.x == 0) partial[blockIdx.x] = red[0];
}

__global__ void scanp_kernel(int* __restrict__ partial, int* __restrict__ rowptr) {
    if (threadIdx.x == 0 && blockIdx.x == 0) {
        int acc = 0;
        for (int i = 0; i < NCH; ++i) {
            int v = partial[i];
            partial[i] = acc;
            acc += v;
        }
        rowptr[NN] = NE;
    }
}

__global__ void scanf_kernel(const int* __restrict__ deg, const int* __restrict__ partial,
                             int* __restrict__ rowptr) {
    __shared__ int buf[512];
    int t = threadIdx.x;
    int idx = blockIdx.x * 512 + t;
    int v = (idx < NN) ? deg[idx] : 0;
    buf[t] = v;
    __syncthreads();
    for (int off = 1; off < 512; off <<= 1) {
        int add = (t >= off) ? buf[t - off] : 0;
        __syncthreads();
        buf[t] += add;
        __syncthreads();
    }
    if (idx < NN) rowptr[idx] = buf[t] - v + partial[blockIdx.x];
}

// ---------------- CSR fill ----------------
__global__ void fill_kernel(const int* __restrict__ src, const int* __restrict__ dst,
                            const int* __restrict__ rowptr, int* __restrict__ cursor,
                            int* __restrict__ col) {
    int i = blockIdx.x * blockDim.x + threadIdx.x;
    int stride = gridDim.x * blockDim.x;
    for (; i < NE; i += stride) {
        int d = dst[i];
        int pos = atomicAdd(&cursor[d], 1);
        col[rowptr[d] + pos] = src[i];
    }
}

// ---------------- gather-sum over 64-dim rows ----------------
// FUSE=false: out[i] = inv_deg[i] * sum x[j]
// FUSE=true : out[i] = inv_deg[i] * sum x[j] + add[i] + bias
template<bool FUSE>
__global__ void gather_kernel(const int* __restrict__ rowptr, const int* __restrict__ col,
                              const float* __restrict__ x, const float* __restrict__ inv_deg,
                              const float* __restrict__ add, const float* __restrict__ bias,
                              float* __restrict__ out) {
    int wave = (blockIdx.x * blockDim.x + threadIdx.x) >> 6;
    int lane = threadIdx.x & 63;
    if (wave >= NN) return;
    int s = rowptr[wave], e = rowptr[wave + 1];
    float acc = 0.f;
    for (int j = s; j < e; ++j) {
        int c = col[j];  // wave-uniform -> broadcast
        acc += x[(size_t)c * 64 + lane];
    }
    float v = acc * inv_deg[wave];
    if (FUSE) v += add[(size_t)wave * 64 + lane] + bias[lane];
    out[(size_t)wave * 64 + lane] = v;
}

// ---------------- tiled GEMM: 128 nodes x 128 outs per block, K=128 blocked by 64 ----
// MODE 1 (layer 1): X = cat(agg, emb) [K: 0..63 agg, 64..127 emb],
//                   W = cat_c(w1l, w1r) [128 x (64+64)], out = relu(XW^T + b1) -> outA[n][0..127]
// MODE 2 (layer 2): X = h [NN][128], W rows: o<64 w2l[o], o>=64 w2r[o-64],
//                   outs 0..63 -> outA (p2), 64..127 -> outB (hz), no bias/relu
template<int MODE>
__global__ void __launch_bounds__(512, 1) gemm_kernel(
        const float* __restrict__ Xa, const float* __restrict__ Xb,
        const float* __restrict__ Wa, const float* __restrict__ Wb,
        const float* __restrict__ bias,
        float* __restrict__ outA, float* __restrict__ outB) {
    __shared__ float lds_x[64 * 128];  // [c_local][node_local]
    __shared__ float lds_w[64 * 128];  // [c_local][o]

    const int tid = threadIdx.x;
    const int n_base = blockIdx.x * 128;

    const int ng = tid & 31;   // nodes 4*ng .. 4*ng+3
    const int og = tid >> 5;   // outs  8*og .. 8*og+7
    const int o0 = og * 8;

    float acc[4][8];
#pragma unroll
    for (int i = 0; i < 4; ++i)
#pragma unroll
        for (int j = 0; j < 8; ++j) acc[i][j] = 0.f;

#pragma unroll
    for (int half = 0; half < 2; ++half) {
        // ---- stage W half (transposed): lds_w[c][o] ----
        {
            int o = tid >> 2;
            int wslot = tid & 3;
#pragma unroll
            for (int k = 0; k < 4; ++k) {
                int s = wslot + 4 * k;   // float4 slot 0..15 within 64 c's
                int c4 = s * 4;          // local c
                float4 v;
                if (MODE == 1) {
                    // row o = cat(w1l[o][0:64], w1r[o][0:64]); half selects source
                    v = (half == 0) ? ((const float4*)Wa)[o * 16 + s]
                                    : ((const float4*)Wb)[o * 16 + s];
                } else {
                    int cg4 = half * 16 + s;  // global c float4 slot (0..31)
                    v = (o < 64) ? ((const float4*)Wa)[o * 32 + cg4]
                                 : ((const float4*)Wb)[(o - 64) * 32 + cg4];
                }
                lds_w[(c4 + 0) * 128 + o] = v.x;
                lds_w[(c4 + 1) * 128 + o] = v.y;
                lds_w[(c4 + 2) * 128 + o] = v.z;
                lds_w[(c4 + 3) * 128 + o] = v.w;
            }
        }
        // ---- stage X half (transposed): lds_x[c][n_local] ----
        {
            int nl = tid >> 2;
            int cslot = tid & 3;
            int n = n_base + nl;
            bool ok = n < NN;
#pragma unroll
            for (int k = 0; k < 4; ++k) {
                int s = cslot + 4 * k;   // 0..15
                int c4 = s * 4;
                float4 v = make_float4(0.f, 0.f, 0.f, 0.f);
                if (ok) {
                    if (MODE == 1) {
                        v = (half == 0) ? ((const float4*)Xa)[(size_t)n * 16 + s]
                                        : ((const float4*)Xb)[(size_t)n * 16 + s];
                    } else {
                        v = ((const float4*)Xa)[(size_t)n * 32 + half * 16 + s];
                    }
                }
                lds_x[(c4 + 0) * 128 + nl] = v.x;
                lds_x[(c4 + 1) * 128 + nl] = v.y;
                lds_x[(c4 + 2) * 128 + nl] = v.z;
                lds_x[(c4 + 3) * 128 + nl] = v.w;
            }
        }
        __syncthreads();

        // ---- compute half ----
#pragma unroll 2
        for (int c = 0; c < 64; ++c) {
            float4 xv = *(const float4*)&lds_x[c * 128 + ng * 4];
            float4 w0 = *(const float4*)&lds_w[c * 128 + o0];
            float4 w1 = *(const float4*)&lds_w[c * 128 + o0 + 4];
            float xr[4] = {xv.x, xv.y, xv.z, xv.w};
            float wr[8] = {w0.x, w0.y, w0.z, w0.w, w1.x, w1.y, w1.z, w1.w};
#pragma unroll
            for (int i = 0; i < 4; ++i)
#pragma unroll
                for (int j = 0; j < 8; ++j) acc[i][j] += xr[i] * wr[j];
        }
        __syncthreads();
    }

    // ---- epilogue ----
    if (MODE == 1) {
        float bj[8];
#pragma unroll
        for (int j = 0; j < 8; ++j) bj[j] = bias[o0 + j];
#pragma unroll
        for (int i = 0; i < 4; ++i) {
            int n = n_base + ng * 4 + i;
            if (n >= NN) continue;
            float4 lo = make_float4(fmaxf(acc[i][0] + bj[0], 0.f), fmaxf(acc[i][1] + bj[1], 0.f),
                                    fmaxf(acc[i][2] + bj[2], 0.f), fmaxf(acc[i][3] + bj[3], 0.f));
            float4 hi = make_float4(fmaxf(acc[i][4] + bj[4], 0.f), fmaxf(acc[i][5] + bj[5], 0.f),
                                    fmaxf(acc[i][6] + bj[6], 0.f), fmaxf(acc[i][7] + bj[7], 0.f));
            ((float4*)outA)[(size_t)n * 32 + (o0 >> 2)] = lo;
            ((float4*)outA)[(size_t)n * 32 + (o0 >> 2) + 1] = hi;
        }
    } else {
        float* dstp = (og < 8) ? outA : outB;
        int ob = (og < 8) ? o0 : (o0 - 64);
#pragma unroll
        for (int i = 0; i < 4; ++i) {
            int n = n_base + ng * 4 + i;
            if (n >= NN) continue;
            float4 lo = make_float4(acc[i][0], acc[i][1], acc[i][2], acc[i][3]);
            float4 hi = make_float4(acc[i][4], acc[i][5], acc[i][6], acc[i][7]);
            ((float4*)dstp)[(size_t)n * 16 + (ob >> 2)] = lo;
            ((float4*)dstp)[(size_t)n * 16 + (ob >> 2) + 1] = hi;
        }
    }
}

// ---------------- decode: out[k] = dot(z[a[k]], z[b[k]]) ----------------
__global__ void decode_kernel(const int* __restrict__ a, const int* __restrict__ b,
                              const float* __restrict__ z, float* __restrict__ out) {
    int t = blockIdx.x * blockDim.x + threadIdx.x;
    int k = t >> 4;
    int q = t & 15;
    if (k >= NL) return;
    int ia = a[k], ib = b[k];
    float4 va = ((const float4*)z)[ia * 16 + q];
    float4 vb = ((const float4*)z)[ib * 16 + q];
    float s = va.x * vb.x + va.y * vb.y + va.z * vb.z + va.w * vb.w;
    s += __shfl_xor(s, 1, 64);
    s += __shfl_xor(s, 2, 64);
    s += __shfl_xor(s, 4, 64);
    s += __shfl_xor(s, 8, 64);
    if (q == 0) out[k] = s;
}

extern "C" void kernel_launch(void* const* d_in, const int* in_sizes, int n_in,
                              void* d_out, int out_size, void* d_ws, size_t ws_size,
                              hipStream_t stream) {
    const float* emb = (const float*)d_in[0];
    const float* w1l = (const float*)d_in[1];
    const float* w1r = (const float*)d_in[2];
    const float* b1  = (const float*)d_in[3];
    const float* w2l = (const float*)d_in[4];
    const float* w2r = (const float*)d_in[5];
    const float* b2  = (const float*)d_in[6];
    const int*   ei  = (const int*)d_in[7];
    const int*   eli = (const int*)d_in[8];
    float* out = (float*)d_out;

    // workspace layout (~110.8 MB), 16B-aligned float arrays
    int* ideg    = (int*)d_ws;                 // NN
    int* rowptr  = ideg + NN;                  // NN+4 (padded for alignment)
    int* cursor  = rowptr + NN + 4;            // NN
    int* partial = cursor + NN;                // 251 (pad so col.. stays aligned)
    int* col     = partial + 251;              // NE
    float* inv_deg = (float*)(col + NE);       // NN
    float* agg   = inv_deg + NN;               // NN*64  (later reused as hz)
    float* h     = agg + (size_t)NN * 64;      // NN*128 (later reused as z)
    float* p2    = h + (size_t)NN * 128;       // NN*64
    float* hz    = agg;
    float* z     = h;

    const int* src = ei;
    const int* dst = ei + NE;

    hipMemsetAsync(ideg, 0, NN * sizeof(int), stream);
    hipMemsetAsync(cursor, 0, NN * sizeof(int), stream);

    // CSR build
    deg_kernel<<<2048, 256, 0, stream>>>(dst, ideg);
    inv_kernel<<<(NN + 255) / 256, 256, 0, stream>>>(ideg, inv_deg);
    partial_kernel<<<NCH, 256, 0, stream>>>(ideg, partial);
    scanp_kernel<<<1, 64, 0, stream>>>(partial, rowptr);
    scanf_kernel<<<NCH, 512, 0, stream>>>(ideg, partial, rowptr);
    fill_kernel<<<2048, 256, 0, stream>>>(src, dst, rowptr, cursor, col);

    const int NT = (NN + 127) / 128;  // 782 tiles

    // layer 1: agg = gather(emb); h = relu(cat(agg,emb) @ cat(w1l,w1r)^T + b1)
    gather_kernel<false><<<(NN * 64 + 255) / 256, 256, 0, stream>>>(
        rowptr, col, emb, inv_deg, nullptr, nullptr, agg);
    gemm_kernel<1><<<NT, 512, 0, stream>>>(agg, emb, w1l, w1r, b1, h, nullptr);

    // layer 2: {p2, hz} = h @ {w2l, w2r}^T ; z = gather(p2) + hz + b2
    gemm_kernel<2><<<NT, 512, 0, stream>>>(h, nullptr, w2l, w2r, nullptr, p2, hz);
    gather_kernel<true><<<(NN * 64 + 255) / 256, 256, 0, stream>>>(
        rowptr, col, p2, inv_deg, hz, b2, z);

    // decode
    decode_kernel<<<(NL * 16 + 255) / 256, 256, 0, stream>>>(eli, eli + NL, z, out);
}

// Round 4
// 496.329 us; speedup vs baseline: 6.9760x; 1.2888x over previous
//
#include <hip/hip_runtime.h>

#define NN   100000
#define EMB  64
#define HID  128
#define OUTD 64
#define NE   1600000
#define NL   200000
#define NCH  196   // ceil(NN/512) scan chunks

// ---------------- degree histogram (int) ----------------
__global__ void deg_kernel(const int* __restrict__ dst, int* __restrict__ deg) {
    int i = blockIdx.x * blockDim.x + threadIdx.x;
    int stride = gridDim.x * blockDim.x;
    for (; i < NE / 4; i += stride) {
        int4 d = ((const int4*)dst)[i];
        atomicAdd(&deg[d.x], 1);
        atomicAdd(&deg[d.y], 1);
        atomicAdd(&deg[d.z], 1);
        atomicAdd(&deg[d.w], 1);
    }
}

__global__ void inv_kernel(const int* __restrict__ deg, float* __restrict__ inv_deg) {
    int i = blockIdx.x * blockDim.x + threadIdx.x;
    if (i < NN) inv_deg[i] = 1.0f / fmaxf((float)deg[i], 1.0f);
}

// ---------------- 2-level exclusive scan: deg -> rowptr ----------------
__global__ void partial_kernel(const int* __restrict__ deg, int* __restrict__ partial) {
    int base = blockIdx.x * 512;
    int s = 0;
    for (int k = threadIdx.x; k < 512; k += 256) {
        int idx = base + k;
        if (idx < NN) s += deg[idx];
    }
    __shared__ int red[256];
    red[threadIdx.x] = s;
    __syncthreads();
    for (int off = 128; off > 0; off >>= 1) {
        if (threadIdx.x < off) red[threadIdx.x] += red[threadIdx.x + off];
        __syncthreads();
    }
    if (threadIdx.x == 0) partial[blockIdx.x] = red[0];
}

__global__ void scanp_kernel(int* __restrict__ partial, int* __restrict__ rowptr) {
    if (threadIdx.x == 0 && blockIdx.x == 0) {
        int acc = 0;
        for (int i = 0; i < NCH; ++i) {
            int v = partial[i];
            partial[i] = acc;
            acc += v;
        }
        rowptr[NN] = NE;
    }
}

__global__ void scanf_kernel(const int* __restrict__ deg, const int* __restrict__ partial,
                             int* __restrict__ rowptr) {
    __shared__ int buf[512];
    int t = threadIdx.x;
    int idx = blockIdx.x * 512 + t;
    int v = (idx < NN) ? deg[idx] : 0;
    buf[t] = v;
    __syncthreads();
    for (int off = 1; off < 512; off <<= 1) {
        int add = (t >= off) ? buf[t - off] : 0;
        __syncthreads();
        buf[t] += add;
        __syncthreads();
    }
    if (idx < NN) rowptr[idx] = buf[t] - v + partial[blockIdx.x];
}

// ---------------- CSR fill (cursor pre-initialized to rowptr) ----------------
__global__ void fill_kernel(const int* __restrict__ src, const int* __restrict__ dst,
                            int* __restrict__ cursor, int* __restrict__ col) {
    int i = blockIdx.x * blockDim.x + threadIdx.x;
    int stride = gridDim.x * blockDim.x;
    for (; i < NE / 4; i += stride) {
        int4 d = ((const int4*)dst)[i];
        int4 s = ((const int4*)src)[i];
        col[atomicAdd(&cursor[d.x], 1)] = s.x;
        col[atomicAdd(&cursor[d.y], 1)] = s.y;
        col[atomicAdd(&cursor[d.z], 1)] = s.z;
        col[atomicAdd(&cursor[d.w], 1)] = s.w;
    }
}

// ---------------- gather-sum over 64-dim rows, 8/4-wide edge-unrolled ----------------
// FUSE=false: out[i] = inv_deg[i] * sum x[j]
// FUSE=true : out[i] = inv_deg[i] * sum x[j] + add[i] + bias
template<bool FUSE>
__global__ void gather_kernel(const int* __restrict__ rowptr, const int* __restrict__ col,
                              const float* __restrict__ x, const float* __restrict__ inv_deg,
                              const float* __restrict__ add, const float* __restrict__ bias,
                              float* __restrict__ out) {
    int wave = (blockIdx.x * blockDim.x + threadIdx.x) >> 6;
    int lane = threadIdx.x & 63;
    if (wave >= NN) return;
    int s = rowptr[wave], e = rowptr[wave + 1];
    float acc = 0.f;
    int j = s;
    for (; j + 8 <= e; j += 8) {
        int c0 = col[j + 0], c1 = col[j + 1], c2 = col[j + 2], c3 = col[j + 3];
        int c4 = col[j + 4], c5 = col[j + 5], c6 = col[j + 6], c7 = col[j + 7];
        float v0 = x[(size_t)c0 * 64 + lane];
        float v1 = x[(size_t)c1 * 64 + lane];
        float v2 = x[(size_t)c2 * 64 + lane];
        float v3 = x[(size_t)c3 * 64 + lane];
        float v4 = x[(size_t)c4 * 64 + lane];
        float v5 = x[(size_t)c5 * 64 + lane];
        float v6 = x[(size_t)c6 * 64 + lane];
        float v7 = x[(size_t)c7 * 64 + lane];
        acc += ((v0 + v1) + (v2 + v3)) + ((v4 + v5) + (v6 + v7));
    }
    if (j + 4 <= e) {
        int c0 = col[j + 0], c1 = col[j + 1], c2 = col[j + 2], c3 = col[j + 3];
        float v0 = x[(size_t)c0 * 64 + lane];
        float v1 = x[(size_t)c1 * 64 + lane];
        float v2 = x[(size_t)c2 * 64 + lane];
        float v3 = x[(size_t)c3 * 64 + lane];
        acc += (v0 + v1) + (v2 + v3);
        j += 4;
    }
    for (; j < e; ++j) acc += x[(size_t)col[j] * 64 + lane];
    float v = acc * inv_deg[wave];
    if (FUSE) v += add[(size_t)wave * 64 + lane] + bias[lane];
    out[(size_t)wave * 64 + lane] = v;
}

// ---------------- tiled GEMM: 128 nodes x 128 outs per block, K=128 blocked by 64 ----
// MODE 1 (layer 1): X = cat(agg, emb), W = cat_c(w1l, w1r), out = relu(XW^T + b1)
// MODE 2 (layer 2): X = h, W rows: o<64 w2l[o], o>=64 w2r[o-64]; outs->outA(p2)/outB(hz)
template<int MODE>
__global__ void __launch_bounds__(512, 1) gemm_kernel(
        const float* __restrict__ Xa, const float* __restrict__ Xb,
        const float* __restrict__ Wa, const float* __restrict__ Wb,
        const float* __restrict__ bias,
        float* __restrict__ outA, float* __restrict__ outB) {
    __shared__ float lds_x[64 * 128];  // [c_local][node_local]
    __shared__ float lds_w[64 * 128];  // [c_local][o]

    const int tid = threadIdx.x;
    const int n_base = blockIdx.x * 128;

    const int ng = tid & 31;   // nodes 4*ng .. 4*ng+3
    const int og = tid >> 5;   // outs  8*og .. 8*og+7
    const int o0 = og * 8;

    float acc[4][8];
#pragma unroll
    for (int i = 0; i < 4; ++i)
#pragma unroll
        for (int j = 0; j < 8; ++j) acc[i][j] = 0.f;

#pragma unroll
    for (int half = 0; half < 2; ++half) {
        // ---- stage W half (transposed): lds_w[c][o] ----
        {
            int o = tid >> 2;
            int wslot = tid & 3;
#pragma unroll
            for (int k = 0; k < 4; ++k) {
                int s = wslot + 4 * k;   // float4 slot 0..15 within 64 c's
                int c4 = s * 4;          // local c
                float4 v;
                if (MODE == 1) {
                    v = (half == 0) ? ((const float4*)Wa)[o * 16 + s]
                                    : ((const float4*)Wb)[o * 16 + s];
                } else {
                    int cg4 = half * 16 + s;
                    v = (o < 64) ? ((const float4*)Wa)[o * 32 + cg4]
                                 : ((const float4*)Wb)[(o - 64) * 32 + cg4];
                }
                lds_w[(c4 + 0) * 128 + o] = v.x;
                lds_w[(c4 + 1) * 128 + o] = v.y;
                lds_w[(c4 + 2) * 128 + o] = v.z;
                lds_w[(c4 + 3) * 128 + o] = v.w;
            }
        }
        // ---- stage X half (transposed): lds_x[c][n_local] ----
        {
            int nl = tid >> 2;
            int cslot = tid & 3;
            int n = n_base + nl;
            bool ok = n < NN;
#pragma unroll
            for (int k = 0; k < 4; ++k) {
                int s = cslot + 4 * k;   // 0..15
                int c4 = s * 4;
                float4 v = make_float4(0.f, 0.f, 0.f, 0.f);
                if (ok) {
                    if (MODE == 1) {
                        v = (half == 0) ? ((const float4*)Xa)[(size_t)n * 16 + s]
                                        : ((const float4*)Xb)[(size_t)n * 16 + s];
                    } else {
                        v = ((const float4*)Xa)[(size_t)n * 32 + half * 16 + s];
                    }
                }
                lds_x[(c4 + 0) * 128 + nl] = v.x;
                lds_x[(c4 + 1) * 128 + nl] = v.y;
                lds_x[(c4 + 2) * 128 + nl] = v.z;
                lds_x[(c4 + 3) * 128 + nl] = v.w;
            }
        }
        __syncthreads();

        // ---- compute half ----
#pragma unroll 2
        for (int c = 0; c < 64; ++c) {
            float4 xv = *(const float4*)&lds_x[c * 128 + ng * 4];
            float4 w0 = *(const float4*)&lds_w[c * 128 + o0];
            float4 w1 = *(const float4*)&lds_w[c * 128 + o0 + 4];
            float xr[4] = {xv.x, xv.y, xv.z, xv.w};
            float wr[8] = {w0.x, w0.y, w0.z, w0.w, w1.x, w1.y, w1.z, w1.w};
#pragma unroll
            for (int i = 0; i < 4; ++i)
#pragma unroll
                for (int j = 0; j < 8; ++j) acc[i][j] += xr[i] * wr[j];
        }
        __syncthreads();
    }

    // ---- epilogue ----
    if (MODE == 1) {
        float bj[8];
#pragma unroll
        for (int j = 0; j < 8; ++j) bj[j] = bias[o0 + j];
#pragma unroll
        for (int i = 0; i < 4; ++i) {
            int n = n_base + ng * 4 + i;
            if (n >= NN) continue;
            float4 lo = make_float4(fmaxf(acc[i][0] + bj[0], 0.f), fmaxf(acc[i][1] + bj[1], 0.f),
                                    fmaxf(acc[i][2] + bj[2], 0.f), fmaxf(acc[i][3] + bj[3], 0.f));
            float4 hi = make_float4(fmaxf(acc[i][4] + bj[4], 0.f), fmaxf(acc[i][5] + bj[5], 0.f),
                                    fmaxf(acc[i][6] + bj[6], 0.f), fmaxf(acc[i][7] + bj[7], 0.f));
            ((float4*)outA)[(size_t)n * 32 + (o0 >> 2)] = lo;
            ((float4*)outA)[(size_t)n * 32 + (o0 >> 2) + 1] = hi;
        }
    } else {
        float* dstp = (og < 8) ? outA : outB;
        int ob = (og < 8) ? o0 : (o0 - 64);
#pragma unroll
        for (int i = 0; i < 4; ++i) {
            int n = n_base + ng * 4 + i;
            if (n >= NN) continue;
            float4 lo = make_float4(acc[i][0], acc[i][1], acc[i][2], acc[i][3]);
            float4 hi = make_float4(acc[i][4], acc[i][5], acc[i][6], acc[i][7]);
            ((float4*)dstp)[(size_t)n * 16 + (ob >> 2)] = lo;
            ((float4*)dstp)[(size_t)n * 16 + (ob >> 2) + 1] = hi;
        }
    }
}

// ---------------- decode: out[k] = dot(z[a[k]], z[b[k]]) ----------------
__global__ void decode_kernel(const int* __restrict__ a, const int* __restrict__ b,
                              const float* __restrict__ z, float* __restrict__ out) {
    int t = blockIdx.x * blockDim.x + threadIdx.x;
    int k = t >> 4;
    int q = t & 15;
    if (k >= NL) return;
    int ia = a[k], ib = b[k];
    float4 va = ((const float4*)z)[ia * 16 + q];
    float4 vb = ((const float4*)z)[ib * 16 + q];
    float s = va.x * vb.x + va.y * vb.y + va.z * vb.z + va.w * vb.w;
    s += __shfl_xor(s, 1, 64);
    s += __shfl_xor(s, 2, 64);
    s += __shfl_xor(s, 4, 64);
    s += __shfl_xor(s, 8, 64);
    if (q == 0) out[k] = s;
}

extern "C" void kernel_launch(void* const* d_in, const int* in_sizes, int n_in,
                              void* d_out, int out_size, void* d_ws, size_t ws_size,
                              hipStream_t stream) {
    const float* emb = (const float*)d_in[0];
    const float* w1l = (const float*)d_in[1];
    const float* w1r = (const float*)d_in[2];
    const float* b1  = (const float*)d_in[3];
    const float* w2l = (const float*)d_in[4];
    const float* w2r = (const float*)d_in[5];
    const float* b2  = (const float*)d_in[6];
    const int*   ei  = (const int*)d_in[7];
    const int*   eli = (const int*)d_in[8];
    float* out = (float*)d_out;

    // workspace layout (~110.8 MB), 16B-aligned float arrays
    int* ideg    = (int*)d_ws;                 // NN
    int* rowptr  = ideg + NN;                  // NN+4 (padded for alignment)
    int* cursor  = rowptr + NN + 4;            // NN
    int* partial = cursor + NN;                // 251 (pad so col.. stays aligned)
    int* col     = partial + 251;              // NE
    float* inv_deg = (float*)(col + NE);       // NN
    float* agg   = inv_deg + NN;               // NN*64  (later reused as hz)
    float* h     = agg + (size_t)NN * 64;      // NN*128 (later reused as z)
    float* p2    = h + (size_t)NN * 128;       // NN*64
    float* hz    = agg;
    float* z     = h;

    const int* src = ei;
    const int* dst = ei + NE;

    hipMemsetAsync(ideg, 0, NN * sizeof(int), stream);

    // CSR build
    deg_kernel<<<1024, 256, 0, stream>>>(dst, ideg);
    inv_kernel<<<(NN + 255) / 256, 256, 0, stream>>>(ideg, inv_deg);
    partial_kernel<<<NCH, 256, 0, stream>>>(ideg, partial);
    scanp_kernel<<<1, 64, 0, stream>>>(partial, rowptr);
    scanf_kernel<<<NCH, 512, 0, stream>>>(ideg, partial, rowptr);
    hipMemcpyAsync(cursor, rowptr, NN * sizeof(int), hipMemcpyDeviceToDevice, stream);
    fill_kernel<<<1024, 256, 0, stream>>>(src, dst, cursor, col);

    const int NT = (NN + 127) / 128;  // 782 tiles

    // layer 1: agg = gather(emb); h = relu(cat(agg,emb) @ cat(w1l,w1r)^T + b1)
    gather_kernel<false><<<(NN * 64 + 255) / 256, 256, 0, stream>>>(
        rowptr, col, emb, inv_deg, nullptr, nullptr, agg);
    gemm_kernel<1><<<NT, 512, 0, stream>>>(agg, emb, w1l, w1r, b1, h, nullptr);

    // layer 2: {p2, hz} = h @ {w2l, w2r}^T ; z = gather(p2) + hz + b2
    gemm_kernel<2><<<NT, 512, 0, stream>>>(h, nullptr, w2l, w2r, nullptr, p2, hz);
    gather_kernel<true><<<(NN * 64 + 255) / 256, 256, 0, stream>>>(
        rowptr, col, p2, inv_deg, hz, b2, z);

    // decode
    decode_kernel<<<(NL * 16 + 255) / 256, 256, 0, stream>>>(eli, eli + NL, z, out);
}